// Round 1
// 433.685 us; speedup vs baseline: 1.0364x; 1.0364x over previous
//
#include <hip/hip_runtime.h>
#include <hip/hip_bf16.h>

#define NN 100000
#define NE 1200000
#define SCAN_B 256
#define NBLK ((NN + SCAN_B - 1) / SCAN_B)   // 391
#define NE4 (NE / 4)                         // 300000
#define AGG_NPW 4                            // nodes per wave in aggmm

// ---------------- slot pass: slot[e] = position of edge within its dst bucket; deg counts ----------------
__global__ __launch_bounds__(256) void slot_kernel(const int* __restrict__ dst,
                                                   int* __restrict__ deg,
                                                   int* __restrict__ slot) {
    int i = blockIdx.x * 256 + threadIdx.x;
    if (i < NE4) {
        int4 d = ((const int4*)dst)[i];
        int4 s;
        s.x = atomicAdd(&deg[d.x], 1);
        s.y = atomicAdd(&deg[d.y], 1);
        s.z = atomicAdd(&deg[d.z], 1);
        s.w = atomicAdd(&deg[d.w], 1);
        ((int4*)slot)[i] = s;
    }
}

__global__ __launch_bounds__(256) void dinv_kernel(const int* __restrict__ deg,
                                                   float* __restrict__ dinv) {
    int n = blockIdx.x * 256 + threadIdx.x;
    if (n < NN) dinv[n] = rsqrtf((float)(deg[n] + 1));  // +1 self loop
}

// ---------------- exclusive scan of deg -> rowptr ----------------
__global__ __launch_bounds__(SCAN_B) void scan1_kernel(const int* __restrict__ deg,
                                                       int* __restrict__ rowptr,
                                                       int* __restrict__ bsum) {
    __shared__ int s[SCAN_B];
    int tid = threadIdx.x;
    int n = blockIdx.x * SCAN_B + tid;
    int d = (n < NN) ? deg[n] : 0;
    s[tid] = d;
    for (int off = 1; off < SCAN_B; off <<= 1) {
        __syncthreads();
        int t = (tid >= off) ? s[tid - off] : 0;
        __syncthreads();
        s[tid] += t;
    }
    if (n <= NN) rowptr[n] = s[tid] - d;            // exclusive, partial
    if (tid == SCAN_B - 1) bsum[blockIdx.x] = s[tid];
}

__global__ __launch_bounds__(512) void scan2_kernel(int* __restrict__ bsum,
                                                    int* __restrict__ boff) {
    __shared__ int s[512];
    int tid = threadIdx.x;
    int v = (tid < NBLK) ? bsum[tid] : 0;
    s[tid] = v;
    for (int off = 1; off < 512; off <<= 1) {
        __syncthreads();
        int t = (tid >= off) ? s[tid - off] : 0;
        __syncthreads();
        s[tid] += t;
    }
    if (tid < NBLK) boff[tid] = s[tid] - v;         // exclusive block offsets
}

__global__ __launch_bounds__(SCAN_B) void scan3_kernel(int* __restrict__ rowptr,
                                                       const int* __restrict__ boff) {
    int n = blockIdx.x * SCAN_B + threadIdx.x;
    if (n < NN) rowptr[n] += boff[blockIdx.x];
    if (n == NN - 1) rowptr[NN] = NE;
}

// ---------------- CSR fill (no atomics): csr[rowptr[dst]+slot] = src ----------------
__global__ __launch_bounds__(256) void fill_kernel(const int* __restrict__ src,
                                                   const int* __restrict__ dst,
                                                   const int* __restrict__ slot,
                                                   const int* __restrict__ rowptr,
                                                   int* __restrict__ csr) {
    int i = blockIdx.x * 256 + threadIdx.x;
    if (i < NE4) {
        int4 d  = ((const int4*)dst)[i];
        int4 sl = ((const int4*)slot)[i];
        int4 sr = ((const int4*)src)[i];
        csr[rowptr[d.x] + sl.x] = sr.x;
        csr[rowptr[d.y] + sl.y] = sr.y;
        csr[rowptr[d.z] + sl.z] = sr.z;
        csr[rowptr[d.w] + sl.w] = sr.w;
    }
}

// ---------------- layer-0 matmul: u = bf16(dinv * (x @ W0)) ----------------
__global__ __launch_bounds__(256) void mm0_kernel(const float* __restrict__ in,
                                                  const float* __restrict__ W,
                                                  const float* __restrict__ dinv,
                                                  __hip_bfloat16* __restrict__ u) {
    __shared__ float Ws[64 * 64];
    __shared__ float hrow[4][64];
    int tid = threadIdx.x;
    {   // stage W (16 KB) via float4
        const float4* Wv = (const float4*)W;
        float4* Wsv = (float4*)Ws;
        #pragma unroll
        for (int i = 0; i < 4; ++i) Wsv[tid + 256 * i] = Wv[tid + 256 * i];
    }
    int local = tid >> 6;            // node within block
    int f = tid & 63;                // feature
    int n = blockIdx.x * 4 + local;  // NN divisible by 4
    float din = dinv[n];
    hrow[local][f] = in[n * 64 + f];
    __syncthreads();
    float acc = 0.f;
    #pragma unroll
    for (int k = 0; k < 64; ++k)
        acc = fmaf(hrow[local][k], Ws[k * 64 + f], acc);
    u[n * 64 + f] = __float2bfloat16(din * acc);
}

// ---------------- shared aggregation core ----------------
// wave layout: 8 groups x 8 lanes. group = edge slot (8 edges in flight),
// fo = feature octet: lane handles features [8*fo, 8*fo+8) via one dwordx4 (16B) per edge.
// CSR row is batch-loaded (one coalesced load per <=64 edges) and broadcast via shfl,
// so the per-edge dependent chain is shfl -> gather (one memory level deep).
// After the xor-butterfly every lane holds the full row sum for its feature octet.
__device__ __forceinline__ void acc_bf8(float acc[8], uint4 v) {
    acc[0] += __uint_as_float(v.x << 16);
    acc[1] += __uint_as_float(v.x & 0xffff0000u);
    acc[2] += __uint_as_float(v.y << 16);
    acc[3] += __uint_as_float(v.y & 0xffff0000u);
    acc[4] += __uint_as_float(v.z << 16);
    acc[5] += __uint_as_float(v.z & 0xffff0000u);
    acc[6] += __uint_as_float(v.w << 16);
    acc[7] += __uint_as_float(v.w & 0xffff0000u);
}

__device__ __forceinline__ void agg_row(const int* __restrict__ rowptr,
                                        const int* __restrict__ csr,
                                        const uint4* __restrict__ u4,
                                        int n, int lane, int grp, int fo,
                                        float acc[8]) {
    #pragma unroll
    for (int i = 0; i < 8; ++i) acc[i] = 0.f;
    if (grp == 0) acc_bf8(acc, u4[n * 8 + fo]);      // self loop
    int start = rowptr[n], end = rowptr[n + 1];
    for (int base = start; base < end; base += 64) {
        int bcnt = end - base; if (bcnt > 64) bcnt = 64;
        int cidx = 0;
        if (lane < bcnt) cidx = csr[base + lane];     // one coalesced batch load
        int nt = (bcnt + 7) >> 3;
        for (int t = 0; t < nt; ++t) {                // uniform trip count: shfl under full exec
            int j = grp + t * 8;
            int s = __shfl(cidx, j < bcnt ? j : 0);
            if (j < bcnt) acc_bf8(acc, u4[s * 8 + fo]);  // 8 independent 128B gathers in flight
        }
    }
    #pragma unroll
    for (int i = 0; i < 8; ++i) {                     // reduce across the 8 edge groups
        acc[i] += __shfl_xor(acc[i], 8);
        acc[i] += __shfl_xor(acc[i], 16);
        acc[i] += __shfl_xor(acc[i], 32);
    }
}

// ---------------- fused aggregate + finalize(prev layer) + matmul(this layer) ----------------
// uout[n][f] = bf16( dinv[n] * sum_k relu(dinv[n]*agg[k] + bias[k]) * W[k][f] )
__global__ __launch_bounds__(256) void aggmm_kernel(const int* __restrict__ rowptr,
                                                    const int* __restrict__ csr,
                                                    const uint4* __restrict__ uin,
                                                    const float* __restrict__ W,
                                                    const float* __restrict__ bias,
                                                    const float* __restrict__ dinv,
                                                    __hip_bfloat16* __restrict__ uout) {
    __shared__ float Ws[64 * 64];
    int tid = threadIdx.x;
    {
        const float4* Wv = (const float4*)W;
        float4* Wsv = (float4*)Ws;
        #pragma unroll
        for (int i = 0; i < 4; ++i) Wsv[tid + 256 * i] = Wv[tid + 256 * i];
    }
    __syncthreads();
    int wid = tid >> 6;
    int lane = tid & 63;
    int grp = lane >> 3;
    int fo = lane & 7;
    float bso[8];                                     // bias slice, hoisted (loop-invariant)
    {
        float4 blo = ((const float4*)bias)[fo * 2];
        float4 bhi = ((const float4*)bias)[fo * 2 + 1];
        bso[0] = blo.x; bso[1] = blo.y; bso[2] = blo.z; bso[3] = blo.w;
        bso[4] = bhi.x; bso[5] = bhi.y; bso[6] = bhi.z; bso[7] = bhi.w;
    }
    int nbase = (blockIdx.x * 4 + wid) * AGG_NPW;     // 6250 blocks x 4 waves x 4 nodes = NN
    for (int ni = 0; ni < AGG_NPW; ++ni) {
        int n = nbase + ni;
        float acc[8];
        agg_row(rowptr, csr, uin, n, lane, grp, fo, acc);
        float din = dinv[n];
        #pragma unroll
        for (int i = 0; i < 8; ++i)
            acc[i] = fmaxf(fmaf(din, acc[i], bso[i]), 0.f);   // finalize prev layer
        // matmul: out[lane] = sum_k row[k] * W[k][lane]; row broadcast via shfl (k static)
        float o = 0.f;
        #pragma unroll
        for (int k = 0; k < 64; ++k) {
            float rv = __shfl(acc[k & 7], k >> 3);
            o = fmaf(rv, Ws[k * 64 + lane], o);
        }
        uout[n * 64 + lane] = __float2bfloat16(din * o);
    }
}

// ---------------- fused final aggregate + pool: g[f] += sum_n dinv[n]*agg[n][f] ----------------
__global__ __launch_bounds__(256) void aggpool_kernel(const int* __restrict__ rowptr,
                                                      const int* __restrict__ csr,
                                                      const uint4* __restrict__ uin,
                                                      const float* __restrict__ dinv,
                                                      float* __restrict__ gsum) {
    __shared__ float gpart[64];
    int tid = threadIdx.x;
    if (tid < 64) gpart[tid] = 0.f;
    __syncthreads();
    int wid = tid >> 6;
    int lane = tid & 63;
    int grp = lane >> 3;
    int fo = lane & 7;
    float pacc[8];
    #pragma unroll
    for (int i = 0; i < 8; ++i) pacc[i] = 0.f;
    for (int n = blockIdx.x * 4 + wid; n < NN; n += gridDim.x * 4) {
        float acc[8];
        agg_row(rowptr, csr, uin, n, lane, grp, fo, acc);
        float din = dinv[n];
        #pragma unroll
        for (int i = 0; i < 8; ++i) pacc[i] = fmaf(din, acc[i], pacc[i]);
    }
    if (grp == 0) {                                   // values replicated across groups; use group 0
        #pragma unroll
        for (int i = 0; i < 8; ++i) atomicAdd(&gpart[fo * 8 + i], pacc[i]);
    }
    __syncthreads();
    if (tid < 64) atomicAdd(&gsum[tid], gpart[tid]);
}

// ---------------- head: out = (g + N*b2) @ Wl + bl ----------------
__global__ __launch_bounds__(64) void head_kernel(const float* __restrict__ g,
                                                  const float* __restrict__ b2,
                                                  const float* __restrict__ Wl,
                                                  const float* __restrict__ bl,
                                                  float* __restrict__ out) {
    int t = threadIdx.x;  // one wave
    float gf = g[t] + (float)NN * b2[t];
    #pragma unroll
    for (int c = 0; c < 10; ++c) {
        float p = gf * Wl[t * 10 + c];
        #pragma unroll
        for (int off = 32; off > 0; off >>= 1) p += __shfl_down(p, off);
        if (t == 0) out[c] = p + bl[c];
    }
}

extern "C" void kernel_launch(void* const* d_in, const int* in_sizes, int n_in,
                              void* d_out, int out_size, void* d_ws, size_t ws_size,
                              hipStream_t stream) {
    const float* x  = (const float*)d_in[0];
    const int* eidx = (const int*)d_in[1];
    const int* esrc = eidx;        // edge_idx[0]
    const int* edst = eidx + NE;   // edge_idx[1]
    const float* W0 = (const float*)d_in[2];
    const float* b0 = (const float*)d_in[3];
    const float* W1 = (const float*)d_in[4];
    const float* b1 = (const float*)d_in[5];
    const float* W2 = (const float*)d_in[6];
    const float* b2 = (const float*)d_in[7];
    const float* Wl = (const float*)d_in[8];
    const float* bl = (const float*)d_in[9];
    float* out = (float*)d_out;

    // workspace layout (4-byte units); ua/ub are 16B-aligned (offsets 200000 / 3400000 floats)
    float* ws = (float*)d_ws;
    size_t off = 0;
    int*   deg    = (int*)(ws + off); off += NN;
    float* dinv   =        ws + off;  off += NN;
    __hip_bfloat16* ua = (__hip_bfloat16*)(ws + off); off += (size_t)NN * 32;  // bf16 N*64
    __hip_bfloat16* ub = (__hip_bfloat16*)(ws + off); off += (size_t)NN * 32;  // bf16 N*64
    float* g      =        ws + off;  off += 64;
    int*   rowptr = (int*)(ws + off); off += NN + 1;
    int*   slot   = (int*)(ws + off); off += NE;
    int*   bsum   = (int*)(ws + off); off += 512;
    int*   boff   = (int*)(ws + off); off += 512;
    int*   csr    = (int*)(ws + off); off += NE;

    hipMemsetAsync(deg, 0, NN * sizeof(int), stream);
    hipMemsetAsync(g, 0, 64 * sizeof(float), stream);

    // norm + CSR build (once; reused by all 3 layers)
    slot_kernel<<<(NE4 + 255) / 256, 256, 0, stream>>>(edst, deg, slot);
    dinv_kernel<<<(NN + 255) / 256, 256, 0, stream>>>(deg, dinv);
    scan1_kernel<<<NBLK, SCAN_B, 0, stream>>>(deg, rowptr, bsum);
    scan2_kernel<<<1, 512, 0, stream>>>(bsum, boff);
    scan3_kernel<<<NBLK, SCAN_B, 0, stream>>>(rowptr, boff);
    fill_kernel<<<(NE4 + 255) / 256, 256, 0, stream>>>(esrc, edst, slot, rowptr, csr);

    // layer 0 matmul
    mm0_kernel<<<NN / 4, 256, 0, stream>>>(x, W0, dinv, ua);
    // fused: agg(layer0) + relu/bias(b0) + matmul(W1)
    aggmm_kernel<<<NN / (4 * AGG_NPW), 256, 0, stream>>>(rowptr, csr, (const uint4*)ua, W1, b0, dinv, ub);
    // fused: agg(layer1) + relu/bias(b1) + matmul(W2)
    aggmm_kernel<<<NN / (4 * AGG_NPW), 256, 0, stream>>>(rowptr, csr, (const uint4*)ub, W2, b1, dinv, ua);
    // fused: agg(layer2) + pool (dinv folded; N*b2 added in head)
    aggpool_kernel<<<2048, 256, 0, stream>>>(rowptr, csr, (const uint4*)ua, dinv, g);
    head_kernel<<<1, 64, 0, stream>>>(g, b2, Wl, bl, out);
}